// Round 12
// baseline (116.115 us; speedup 1.0000x reference)
//
#include <hip/hip_runtime.h>
#include <math.h>

#define PROJ 8192
#define NB   16
#define NC   512
#define HW   196      // 14*14
#define KP   224      // K padded (zero-filled 196..224 by prep)
#define LSK  132      // LDS row stride (elems) for staged halves (128+4 pad)
#define XELE ((size_t)NB * NC * KP)

typedef __attribute__((ext_vector_type(8))) short bf16x8;   // 16 B MFMA frag
typedef __attribute__((ext_vector_type(4))) short short4v;
typedef __attribute__((ext_vector_type(4))) float f32x4;

__device__ __forceinline__ unsigned bf16_rne(float f) {
    unsigned u = __builtin_bit_cast(unsigned, f);
    return (u + 0x7fffu + ((u >> 16) & 1u)) >> 16;
}

// ---------------------------------------------------------------------------
// Kernel 0 (prep): x fp32 -> xh/xl bf16 [8192 x 224], K zero-padded.
// XCD-pinned: block e+8t handles batch pair (2e,2e+1). grid = 1792.
// ---------------------------------------------------------------------------
__global__ __launch_bounds__(256)
void cbp_prep(const float* __restrict__ x,
              short* __restrict__ xh, short* __restrict__ xl) {
    const int e    = blockIdx.x & 7;
    const int t    = blockIdx.x >> 3;
    const int task = t * 256 + threadIdx.x;
    const int q    = task % 56;
    const int rp   = task / 56;
    const int row  = e * 1024 + rp;
    float4 v = {0.f, 0.f, 0.f, 0.f};
    if (q < 49) v = *(const float4*)&x[(size_t)row * HW + 4 * q];
    const float f[4] = {v.x, v.y, v.z, v.w};
    short4v h, l;
#pragma unroll
    for (int c = 0; c < 4; ++c) {
        const unsigned hb = bf16_rne(f[c]);
        h[c] = (short)hb;
        l[c] = (short)bf16_rne(f[c] - __builtin_bit_cast(float, hb << 16));
    }
    *(short4v*)&xh[(size_t)row * KP + 4 * q] = h;
    *(short4v*)&xl[(size_t)row * KP + 4 * q] = l;
}

// ---------------------------------------------------------------------------
// Kernel 1 (gram): STAGE-ONCE structure. 576 blocks x 256 thr (4 waves).
// Upper-triangle 64x64 tiles (36/batch), xcd = blk&7 pins batch pair.
// Half-0 (K=128): 16 independent 16B loads/thread -> LDS, ONE barrier.
// Half-1 (K=96) global loads prefetched into REGISTERS during half-0 MFMA.
// 4 barriers/block total (was 14). Scatter both orientations into private
// 32KB sketch; dense dump. LDS total 100 KB.
// ---------------------------------------------------------------------------
__global__ __launch_bounds__(256)
void cbp_gram(const short* __restrict__ xh, const short* __restrict__ xl,
              const float* __restrict__ s1, const float* __restrict__ s2,
              const int*   __restrict__ h1, const int*   __restrict__ h2,
              float* __restrict__ partials) {
    __shared__ float sk[PROJ];                             // 32 KB
    __shared__ short Ah[64 * LSK], Al[64 * LSK];           // 16.5 KB each
    __shared__ short Bh[64 * LSK], Bl[64 * LSK];
    __shared__ int   rh1[64], rh2[64], ch1[64], ch2[64];
    __shared__ float rs1[64], rs2[64], cs1[64], cs2[64];

    const int tid = threadIdx.x;
    const int blk = blockIdx.x;
    const int xcd = blk & 7;
    const int idx = blk >> 3;                  // 0..71
    const int hi  = (idx >= 36) ? 1 : 0;
    const int b   = 2 * xcd + hi;
    int I = 0, uu = idx - 36 * hi;
    while (uu >= 8 - I) { uu -= 8 - I; ++I; }  // upper-tri decode (uniform)
    const int J = I + uu;
    const int c1base = I * 64, c2base = J * 64;

    for (int i = tid; i < PROJ / 4; i += 256)
        ((float4*)sk)[i] = (float4){0.f, 0.f, 0.f, 0.f};
    if (tid < 64) {
        rh1[tid] = h1[c1base + tid]; rh2[tid] = h2[c1base + tid];
        rs1[tid] = s1[c1base + tid]; rs2[tid] = s2[c1base + tid];
    } else if (tid < 128) {
        const int t = tid - 64;
        ch1[t] = h1[c2base + t]; ch2[t] = h2[c2base + t];
        cs1[t] = s1[c2base + t]; cs2[t] = s2[c2base + t];
    }

    // ---- Stage half-0 (cols 0..127): 16 loads/thread, all independent ----
    const int srow = tid >> 2;                 // 0..63
    const int sq   = tid & 3;                  // 0..3
    const size_t gA = ((size_t)b * NC + c1base + srow) * KP;
    const size_t gB = ((size_t)b * NC + c2base + srow) * KP;
#pragma unroll
    for (int i = 0; i < 4; ++i) {
        const int s = sq + 4 * i;              // slot 0..15 (col 8s)
        *(bf16x8*)&Ah[srow * LSK + 8 * s] = *(const bf16x8*)&xh[gA + 8 * s];
        *(bf16x8*)&Al[srow * LSK + 8 * s] = *(const bf16x8*)&xl[gA + 8 * s];
        *(bf16x8*)&Bh[srow * LSK + 8 * s] = *(const bf16x8*)&xh[gB + 8 * s];
        *(bf16x8*)&Bl[srow * LSK + 8 * s] = *(const bf16x8*)&xl[gB + 8 * s];
    }
    __syncthreads();                           // barrier 1

    // ---- Prefetch half-1 (cols 128..223) into registers ----
    bf16x8 p[12];                              // 3 slots x 4 arrays
#pragma unroll
    for (int i = 0; i < 3; ++i) {
        const int s = sq + 4 * i;              // slot 0..11 (col 128+8s)
        p[4 * i + 0] = *(const bf16x8*)&xh[gA + 128 + 8 * s];
        p[4 * i + 1] = *(const bf16x8*)&xl[gA + 128 + 8 * s];
        p[4 * i + 2] = *(const bf16x8*)&xh[gB + 128 + 8 * s];
        p[4 * i + 3] = *(const bf16x8*)&xl[gB + 128 + 8 * s];
    }

    const int lane = tid & 63, wave = tid >> 6;
    const int quad = lane >> 4, l15 = lane & 15;
    const int wr = (wave >> 1) * 32, wc = (wave & 1) * 32;

    f32x4 acc[2][2];
#pragma unroll
    for (int i = 0; i < 2; ++i)
#pragma unroll
        for (int j = 0; j < 2; ++j) acc[i][j] = (f32x4){0.f, 0.f, 0.f, 0.f};

    // ---- MFMA half-0: 4 chunks, LDS-only, no barriers ----
#pragma unroll
    for (int c = 0; c < 4; ++c) {
        const int col = 32 * c + quad * 8;
        bf16x8 ahf[2], alf[2], bhf[2], blf[2];
#pragma unroll
        for (int i = 0; i < 2; ++i) {
            const int ra = wr + 16 * i + l15;
            const int rb = wc + 16 * i + l15;
            ahf[i] = *(const bf16x8*)&Ah[ra * LSK + col];
            alf[i] = *(const bf16x8*)&Al[ra * LSK + col];
            bhf[i] = *(const bf16x8*)&Bh[rb * LSK + col];
            blf[i] = *(const bf16x8*)&Bl[rb * LSK + col];
        }
#pragma unroll
        for (int i = 0; i < 2; ++i)
#pragma unroll
            for (int j = 0; j < 2; ++j) {
                acc[i][j] = __builtin_amdgcn_mfma_f32_16x16x32_bf16(ahf[i], bhf[j], acc[i][j], 0, 0, 0);
                acc[i][j] = __builtin_amdgcn_mfma_f32_16x16x32_bf16(ahf[i], blf[j], acc[i][j], 0, 0, 0);
                acc[i][j] = __builtin_amdgcn_mfma_f32_16x16x32_bf16(alf[i], bhf[j], acc[i][j], 0, 0, 0);
            }
    }
    __syncthreads();                           // barrier 2 (half-0 reads done)

    // ---- Store half-1 from registers ----
#pragma unroll
    for (int i = 0; i < 3; ++i) {
        const int s = sq + 4 * i;
        *(bf16x8*)&Ah[srow * LSK + 8 * s] = p[4 * i + 0];
        *(bf16x8*)&Al[srow * LSK + 8 * s] = p[4 * i + 1];
        *(bf16x8*)&Bh[srow * LSK + 8 * s] = p[4 * i + 2];
        *(bf16x8*)&Bl[srow * LSK + 8 * s] = p[4 * i + 3];
    }
    __syncthreads();                           // barrier 3

    // ---- MFMA half-1: 3 chunks ----
#pragma unroll
    for (int c = 0; c < 3; ++c) {
        const int col = 32 * c + quad * 8;
        bf16x8 ahf[2], alf[2], bhf[2], blf[2];
#pragma unroll
        for (int i = 0; i < 2; ++i) {
            const int ra = wr + 16 * i + l15;
            const int rb = wc + 16 * i + l15;
            ahf[i] = *(const bf16x8*)&Ah[ra * LSK + col];
            alf[i] = *(const bf16x8*)&Al[ra * LSK + col];
            bhf[i] = *(const bf16x8*)&Bh[rb * LSK + col];
            blf[i] = *(const bf16x8*)&Bl[rb * LSK + col];
        }
#pragma unroll
        for (int i = 0; i < 2; ++i)
#pragma unroll
            for (int j = 0; j < 2; ++j) {
                acc[i][j] = __builtin_amdgcn_mfma_f32_16x16x32_bf16(ahf[i], bhf[j], acc[i][j], 0, 0, 0);
                acc[i][j] = __builtin_amdgcn_mfma_f32_16x16x32_bf16(ahf[i], blf[j], acc[i][j], 0, 0, 0);
                acc[i][j] = __builtin_amdgcn_mfma_f32_16x16x32_bf16(alf[i], bhf[j], acc[i][j], 0, 0, 0);
            }
    }

    // ---- Scatter both orientations. C/D: col=lane&15, row=quad*4+reg ----
    const bool offd = (I != J);
#pragma unroll
    for (int i = 0; i < 2; ++i) {
        const int r0 = wr + i * 16 + quad * 4;
#pragma unroll
        for (int j = 0; j < 2; ++j) {
            const int c = wc + j * 16 + l15;
            const int ch2v = ch2[c], ch1v = ch1[c];
            const float cs2v = cs2[c], cs1v = cs1[c];
#pragma unroll
            for (int rg = 0; rg < 4; ++rg) {
                const int r = r0 + rg;
                const float g = acc[i][j][rg];
                atomicAdd(&sk[(rh1[r] + ch2v) & (PROJ - 1)], rs1[r] * cs2v * g);
                if (offd)
                    atomicAdd(&sk[(ch1v + rh2[r]) & (PROJ - 1)], cs1v * rs2[r] * g);
            }
        }
    }
    __syncthreads();                           // barrier 4

    float4* dst = (float4*)(partials + (size_t)blk * PROJ);
    const float4* src = (const float4*)sk;
    for (int i = tid; i < PROJ / 4; i += 256) dst[i] = src[i];
}

// ---------------------------------------------------------------------------
// Kernel 2 (reduce): sum 36 partials/bin + signed sqrt + per-block ssq.
// grid = 512; blk&7 matches gram's XCD pin.
// ---------------------------------------------------------------------------
__global__ __launch_bounds__(256)
void cbp_reduce(const float* __restrict__ partials, float* __restrict__ y,
                float* __restrict__ ssqp) {
    const int blk = blockIdx.x;
    const int xcd = blk & 7;
    const int k   = blk >> 3;          // 0..63
    const int hi  = k >> 5;
    const int seg = k & 31;
    const int b   = 2 * xcd + hi;
    const int tid = threadIdx.x;
    const int bin = seg * 256 + tid;

    float s = 0.f;
#pragma unroll
    for (int u = 0; u < 36; ++u) {
        int u2 = u + seg; if (u2 >= 36) u2 -= 36;      // rotate partial order
        const int pb = ((hi * 36 + u2) << 3) | xcd;
        s += partials[(size_t)pb * PROJ + bin];
    }

    const float m = sqrtf(fabsf(s) + 1e-8f);
    const float o = (s > 0.f) ? m : (s < 0.f ? -m : 0.f);   // sign(0)=0
    y[b * PROJ + bin] = o;

    __shared__ float red[256];
    red[tid] = o * o;
    __syncthreads();
#pragma unroll
    for (int st = 128; st >= 1; st >>= 1) {
        if (tid < st) red[tid] += red[tid + st];
        __syncthreads();
    }
    if (tid == 0) ssqp[blk] = red[0];
}

// ---------------------------------------------------------------------------
// Kernel 3 (norm): y_b /= max(||y_b||, 1e-12). grid = 32 (b, half-row).
// ---------------------------------------------------------------------------
__global__ __launch_bounds__(256)
void cbp_normalize(float* __restrict__ y, const float* __restrict__ ssqp) {
    const int b   = blockIdx.x >> 1;
    const int off = (blockIdx.x & 1) * 4096;
    const int tid = threadIdx.x;
    float ssq = 0.f;
#pragma unroll
    for (int seg = 0; seg < 32; ++seg)
        ssq += ssqp[(((b & 1) * 32 + seg) << 3) | (b >> 1)];
    const float inv = 1.0f / fmaxf(sqrtf(ssq), 1e-12f);

    float4* row = (float4*)&y[(size_t)b * PROJ + off];
#pragma unroll
    for (int j = 0; j < 4; ++j) {
        float4 v = row[j * 256 + tid];
        v.x *= inv; v.y *= inv; v.z *= inv; v.w *= inv;
        row[j * 256 + tid] = v;
    }
}

// ---------------------------------------------------------------------------
extern "C" void kernel_launch(void* const* d_in, const int* in_sizes, int n_in,
                              void* d_out, int out_size, void* d_ws, size_t ws_size,
                              hipStream_t stream) {
    const float* x  = (const float*)d_in[0];
    const float* s1 = (const float*)d_in[1];
    const float* s2 = (const float*)d_in[2];
    const int*   h1 = (const int*)d_in[3];
    const int*   h2 = (const int*)d_in[4];
    float* y = (float*)d_out;                    // [16, 8192]

    // ws layout (~26.3 MB used):
    short* xh = (short*)d_ws;                    // 3.67 MB
    short* xl = xh + XELE;                       // 3.67 MB
    float* partials = (float*)(xl + XELE);       // 576 * 32 KB = 18.9 MB
    float* ssqp = partials + (size_t)576 * PROJ; // 512 floats

    hipLaunchKernelGGL(cbp_prep, dim3(1792), dim3(256), 0, stream, x, xh, xl);
    hipLaunchKernelGGL(cbp_gram, dim3(576), dim3(256), 0, stream,
                       xh, xl, s1, s2, h1, h2, partials);
    hipLaunchKernelGGL(cbp_reduce, dim3(512), dim3(256), 0, stream,
                       partials, y, ssqp);
    hipLaunchKernelGGL(cbp_normalize, dim3(32), dim3(256), 0, stream, y, ssqp);
}